// Round 9
// baseline (6284.855 us; speedup 1.0000x reference)
//
#include <hip/hip_runtime.h>
#include <cstdint>
#include <cstddef>

#define NODES   55
#define BGRAPH  16384
#define NTOT    (BGRAPH*NODES)    // 901120
#define INCH    13
#define HID     32
#define ETOT    (4*NTOT)          // 3604480
#define NCHUNK  (NTOT/1024)       // 880 exact
#define NPART   10
#define NQ      (NTOT/NPART)      // 90112 = 704*128
#define EVCAPE  (ETOT/NPART + 6144)   // 366592 rows (+10.8 sigma margin)
#define BMW     (NTOT/32)         // bitmap words per partition

typedef _Float16 f16;
typedef _Float16 f16x4 __attribute__((ext_vector_type(4))); // 8B
typedef _Float16 f16x8 __attribute__((ext_vector_type(8))); // 16B

__device__ __forceinline__ float selu_f(float v){
  const float s  = 1.0507009873554805f;
  const float sa = 1.7580993408473766f;
  return v > 0.f ? s*v : sa*(__expf(v)-1.f);
}

// ---------------- CSR/CSC build ----------------
__global__ void k_hist2(const int* __restrict__ a, const int* __restrict__ b,
                        int* __restrict__ da, int* __restrict__ db){
  int e = blockIdx.x*256 + threadIdx.x;
  if (e < ETOT){ atomicAdd(&da[a[e]], 1); atomicAdd(&db[b[e]], 1); }
}

__global__ void k_scan1(const int* __restrict__ deg, int* __restrict__ part){
  __shared__ int sd[256];
  int b = blockIdx.x, t = threadIdx.x;
  const int4* p = (const int4*)(deg + b*1024);
  int4 v = p[t];
  sd[t] = v.x+v.y+v.z+v.w;
  __syncthreads();
  for (int o=128;o>0;o>>=1){ if (t<o) sd[t]+=sd[t+o]; __syncthreads(); }
  if (t==0) part[b] = sd[0];
}

__global__ void k_scan2(int* __restrict__ part, int nc){
  __shared__ int sd[1024];
  int t = threadIdx.x;
  int orig = (t<nc) ? part[t] : 0;
  sd[t] = orig;
  __syncthreads();
  for (int o=1;o<1024;o<<=1){
    int v = (t>=o) ? sd[t-o] : 0;
    __syncthreads();
    sd[t] += v;
    __syncthreads();
  }
  if (t<nc) part[t] = sd[t] - orig;   // exclusive
}

__global__ void k_scan3(const int* __restrict__ deg, const int* __restrict__ part,
                        int* __restrict__ off){
  __shared__ int sd[256];
  int b = blockIdx.x, t = threadIdx.x;
  const int4* p = (const int4*)(deg + b*1024);
  int4 v = p[t];
  int s = v.x+v.y+v.z+v.w;
  sd[t] = s;
  __syncthreads();
  for (int o=1;o<256;o<<=1){
    int val = (t>=o) ? sd[t-o] : 0;
    __syncthreads();
    sd[t] += val;
    __syncthreads();
  }
  int base = part[b] + sd[t] - s;
  int i = b*1024 + t*4;
  off[i]   = base;
  off[i+1] = base + v.x;
  off[i+2] = base + v.x + v.y;
  off[i+3] = base + v.x + v.y + v.z;
  if (b==0 && t==0) off[NTOT] = ETOT;
}

// mapS[csc_pos] = csr_pos; also set bitmap bit (partition(dst), src)
__global__ void k_fill2(const int* __restrict__ src, const int* __restrict__ dst,
                        int* __restrict__ curS, int* __restrict__ curD,
                        uint32_t* __restrict__ mapS, uint32_t* __restrict__ bm){
  int e = blockIdx.x*256 + threadIdx.x;
  if (e >= ETOT) return;
  int s = src[e], d = dst[e];
  int ps = atomicAdd(&curS[s], 1);
  int pd = atomicAdd(&curD[d], 1);
  mapS[ps] = (uint32_t)pd;
  int q = d / NQ;
  atomicOr(&bm[q*BMW + (s>>5)], 1u << (s&31));
}

// ---------------- fat pipelined layer kernel (layers 1..4) ----------------
// role by blockIdx%6: r==5 -> reduce partition q_rd; else scatter partition q_sc.
__global__ __launch_bounds__(256,8) void k_pipe(
    const f16* __restrict__ hc, f16* __restrict__ hn, f16* __restrict__ jk,
    const int* __restrict__ off, const int* __restrict__ offS,
    const uint32_t* __restrict__ mapS, const uint32_t* __restrict__ bm,
    f16* __restrict__ EVsc, const f16* __restrict__ EVrd,
    const float* __restrict__ wl, const float* __restrict__ bl,
    const float* __restrict__ wr,
    int q_sc, int q_rd)
{
  __shared__ f16 AG[128*34];
  int r = blockIdx.x % 6;
  int g = blockIdx.x / 6;
  int t = threadIdx.x;

  if (r != 5){
    // ================== scatter role ==================
    if (q_sc < 0) return;
    int sb = g*5 + r;                  // 0..3519
    int base = sb*256;
    int lane = t & 3, slot = t >> 2;   // 64 slots, 4 lanes (16B) per edge
    uint32_t ebase = (uint32_t)off[q_sc*NQ];
    uint32_t span  = (uint32_t)off[q_sc*NQ + NQ] - ebase;
    if (span > (uint32_t)EVCAPE) span = EVCAPE;
    const uint32_t* bmq = bm + q_sc*BMW;
    #pragma unroll
    for (int i=0;i<4;i++){
      int s = base + slot + 64*i;
      uint32_t bits = bmq[s>>5];
      if (!((bits >> (s&31)) & 1u)) continue;
      f16x8 hv = *(const f16x8*)(hc + (size_t)s*HID + lane*8);
      int s0 = offS[s], s1 = offS[s+1];
      for (int j=s0;j<s1;j++){
        uint32_t rel = mapS[j] - ebase;
        if (rel < span)
          *(f16x8*)(EVsc + (size_t)rel*HID + lane*8) = hv;
      }
    }
    return;
  }

  // ================== reduce role ==================
  if (q_rd < 0) return;
  int baseN = q_rd*NQ + g*128;
  int ebase = off[q_rd*NQ];
  int l = t & 7, sub = t >> 3;             // 8 lanes (4ch)/node, 32 nodes/pass
  for (int p=0; p<4; p++){
    int nl = p*32 + sub;
    int node = baseN + nl;
    int s0 = off[node], s1 = off[node+1];
    float a0=0.f,a1=0.f,a2=0.f,a3=0.f;
    for (int j=s0; j<s1; j++){
      uint32_t rel = (uint32_t)(j - ebase);
      if (rel >= (uint32_t)EVCAPE) break;
      f16x4 v = *(const f16x4*)(EVrd + (size_t)rel*HID + 4*l);
      a0 += (float)v[0]; a1 += (float)v[1];
      a2 += (float)v[2]; a3 += (float)v[3];
    }
    int cnt = s1-s0; if (cnt<1) cnt=1;
    float inv = 1.f/(float)cnt;
    f16* row = AG + nl*34 + 4*l;
    row[0]=(f16)(a0*inv); row[1]=(f16)(a1*inv);
    row[2]=(f16)(a2*inv); row[3]=(f16)(a3*inv);
  }
  __syncthreads();
  int nl = t & 127;
  int node = baseN + nl;
  int oc0 = __builtin_amdgcn_readfirstlane((t>>7)*16);
  const f16x8* h8 = (const f16x8*)(hc + (size_t)node*HID);
  float acc[16];
  #pragma unroll
  for (int j=0;j<16;j++) acc[j] = bl[oc0+j];
  #pragma unroll
  for (int jj=0;jj<4;jj++){
    f16x8 vh = h8[jj];
    #pragma unroll
    for (int rr=0;rr<8;rr++){
      int cc = 8*jj+rr;
      float hv = (float)vh[rr];
      float mc = (float)AG[nl*34+cc];
      #pragma unroll
      for (int j=0;j<16;j++)
        acc[j] = fmaf(hv, wr[cc*HID+oc0+j], fmaf(mc, wl[cc*HID+oc0+j], acc[j]));
    }
  }
  __syncthreads();
  #pragma unroll
  for (int j=0;j<16;j++) AG[nl*34 + oc0 + j] = (f16)selu_f(acc[j]);
  __syncthreads();
  const uint32_t* STd = (const uint32_t*)AG;
  uint4* ho4 = (uint4*)hn;
  uint4* jo4 = (uint4*)jk;
  size_t gbase = (size_t)baseN * 4;
  #pragma unroll
  for (int k=0;k<2;k++){
    int cch = t + 256*k;
    int n = cch>>2, m = cch&3;
    int d = n*17 + m*4;
    union { uint4 u; f16 hh[8]; } hv2, jv;
    hv2.u.x=STd[d]; hv2.u.y=STd[d+1]; hv2.u.z=STd[d+2]; hv2.u.w=STd[d+3];
    jv.u = jo4[gbase+cch];
    #pragma unroll
    for (int rr=0;rr<8;rr++){
      float a = (float)jv.hh[rr], b = (float)hv2.hh[rr];
      jv.hh[rr] = (f16)fmaxf(a, b);
    }
    ho4[gbase+cch] = hv2.u;
    jo4[gbase+cch] = jv.u;
  }
}

// ---------------- fat pipelined layer-0 kernel ----------------
__global__ __launch_bounds__(256,8) void k_pipe0(
    const float* __restrict__ x, f16* __restrict__ hn, f16* __restrict__ jk,
    const int* __restrict__ off, const int* __restrict__ offS,
    const uint32_t* __restrict__ mapS, const uint32_t* __restrict__ bm,
    float* __restrict__ EVsc, const float* __restrict__ EVrd,
    const float* __restrict__ wl0, const float* __restrict__ bl0,
    const float* __restrict__ wr0,
    int q_sc, int q_rd)
{
  __shared__ float AG0[128*13];
  __shared__ f16   ST0[128*34];
  int r = blockIdx.x % 6;
  int g = blockIdx.x / 6;
  int t = threadIdx.x;

  if (r != 5){
    if (q_sc < 0) return;
    int sb = g*5 + r;
    int base = sb*256;
    int lane = t & 3, slot = t >> 2;
    uint32_t ebase = (uint32_t)off[q_sc*NQ];
    uint32_t span  = (uint32_t)off[q_sc*NQ + NQ] - ebase;
    if (span > (uint32_t)EVCAPE) span = EVCAPE;
    const uint32_t* bmq = bm + q_sc*BMW;
    #pragma unroll
    for (int i=0;i<4;i++){
      int s = base + slot + 64*i;
      uint32_t bits = bmq[s>>5];
      if (!((bits >> (s&31)) & 1u)) continue;
      const float* xr = x + (size_t)s*INCH;
      float4 hv;
      int cb = lane*4;
      hv.x = xr[cb];
      hv.y = (cb+1<INCH)? xr[cb+1] : 0.f;
      hv.z = (cb+2<INCH)? xr[cb+2] : 0.f;
      hv.w = (cb+3<INCH)? xr[cb+3] : 0.f;
      int s0 = offS[s], s1 = offS[s+1];
      for (int j=s0;j<s1;j++){
        uint32_t rel = mapS[j] - ebase;
        if (rel < span)
          *(float4*)(EVsc + (size_t)rel*16 + cb) = hv;
      }
    }
    return;
  }

  if (q_rd < 0) return;
  int baseN = q_rd*NQ + g*128;
  int ebase = off[q_rd*NQ];
  int c = t & 15, sub = t >> 4;
  for (int p=0; p<8; p++){
    int nl = p*16 + sub;
    int node = baseN + nl;
    int s0 = off[node], s1 = off[node+1];
    if (c < INCH){
      float s = 0.f;
      for (int j=s0; j<s1; j++){
        uint32_t rel = (uint32_t)(j - ebase);
        if (rel >= (uint32_t)EVCAPE) break;
        s += EVrd[(size_t)rel*16 + c];
      }
      int cnt = s1-s0; if (cnt<1) cnt=1;
      AG0[nl*INCH + c] = s/(float)cnt;
    }
  }
  __syncthreads();
  int nl = t & 127;
  int node = baseN + nl;
  int oc0 = __builtin_amdgcn_readfirstlane((t>>7)*16);
  const float* xr = x + (size_t)node*INCH;
  float acc[16];
  #pragma unroll
  for (int j=0;j<16;j++) acc[j] = bl0[oc0+j];
  #pragma unroll
  for (int cc=0;cc<INCH;cc++){
    float xc = xr[cc];
    float mc = AG0[nl*INCH+cc];
    #pragma unroll
    for (int j=0;j<16;j++)
      acc[j] = fmaf(xc, wr0[cc*HID+oc0+j], fmaf(mc, wl0[cc*HID+oc0+j], acc[j]));
  }
  #pragma unroll
  for (int j=0;j<16;j++) ST0[nl*34 + oc0 + j] = (f16)selu_f(acc[j]);
  __syncthreads();
  const uint32_t* STd = (const uint32_t*)ST0;
  uint4* ho4 = (uint4*)hn;
  uint4* jo4 = (uint4*)jk;
  size_t gbase = (size_t)baseN * 4;
  #pragma unroll
  for (int k=0;k<2;k++){
    int cch = t + 256*k;
    int n = cch>>2, m = cch&3;
    int d = n*17 + m*4;
    uint4 u;
    u.x=STd[d]; u.y=STd[d+1]; u.z=STd[d+2]; u.w=STd[d+3];
    ho4[gbase+cch] = u;
    jo4[gbase+cch] = u;
  }
}

// ---------------- attention + head, one block per graph ----------------
__global__ __launch_bounds__(256) void k_attn(
    const f16* __restrict__ jk, const float* __restrict__ x,
    const int* __restrict__ shuf,
    const float* __restrict__ wq, const float* __restrict__ bq,
    const float* __restrict__ wk, const float* __restrict__ bk,
    const float* __restrict__ wv, const float* __restrict__ bv,
    const float* __restrict__ wo, const float* __restrict__ bo,
    const float* __restrict__ wfc, const float* __restrict__ bfc,
    float* __restrict__ out)
{
  __shared__ float H[NODES*33];
  __shared__ float K[NODES*33];
  __shared__ float V[NODES*33];
  __shared__ float Wq[HID*HID];
  __shared__ float Wo[HID*HID];
  __shared__ float Wfc[192*6];
  __shared__ float Qs[6*33];
  __shared__ float S[6*56];
  __shared__ float O[6*33];
  __shared__ float SO[192];
  __shared__ float part[96];
  __shared__ float M[NODES];
  __shared__ int order[8];
  __shared__ int sel[6];

  int g = blockIdx.x, t = threadIdx.x;
  for (int i=t; i<HID*HID; i+=256){ Wq[i]=wq[i]; Wo[i]=wo[i]; }
  for (int i=t; i<192*6;   i+=256){ Wfc[i]=wfc[i]; }
  {
    const f16x8* j8 = (const f16x8*)(jk + (size_t)g*NODES*HID);
    for (int i=t; i<NODES*HID/8; i+=256){
      f16x8 v = j8[i];
      int node = i >> 2, c0 = (i & 3)*8;
      #pragma unroll
      for (int r=0;r<8;r++) H[node*33 + c0 + r] = selu_f((float)v[r]);
    }
  }
  if (t < NODES) M[t] = x[(size_t)(g*NODES+t)*INCH + (INCH-3)];
  __syncthreads();
  if (t == 0){
    int c = 0;
    for (int n=0;n<NODES;n++) if (M[n] > 0.5f && c < 6) order[c++] = n;
  }
  __syncthreads();
  if (t < 6) sel[t] = order[shuf[g*6 + t]];
  __syncthreads();

  {
    int k = t & 63;
    int ocg = __builtin_amdgcn_readfirstlane(t >> 6);
    const float* wkp = wk + ocg*8;
    const float* wvp = wv + ocg*8;
    if (k < NODES){
      float ak[8], av[8];
      #pragma unroll
      for (int j=0;j<8;j++){ ak[j]=bk[ocg*8+j]; av[j]=bv[ocg*8+j]; }
      #pragma unroll
      for (int c=0;c<HID;c++){
        float hv = H[k*33+c];
        #pragma unroll
        for (int j=0;j<8;j++){
          ak[j] = fmaf(hv, wkp[c*HID+j], ak[j]);
          av[j] = fmaf(hv, wvp[c*HID+j], av[j]);
        }
      }
      #pragma unroll
      for (int j=0;j<8;j++){ K[k*33+ocg*8+j]=ak[j]; V[k*33+ocg*8+j]=av[j]; }
    }
  }
  if (t < 192){
    int q = t>>5, oc = t&31;
    int node = sel[q];
    float a = bq[oc];
    #pragma unroll
    for (int c=0;c<HID;c++) a = fmaf(H[node*33+c], Wq[c*HID+oc], a);
    Qs[q*33+oc] = a;
  }
  __syncthreads();

  for (int idx=t; idx<6*NODES; idx+=256){
    int q = idx % 6, k = idx / 6;
    float a = 0.f;
    #pragma unroll
    for (int c=0;c<HID;c++) a = fmaf(Qs[q*33+c], K[k*33+c], a);
    S[q*56+k] = a * 0.17677669529663687f;
  }
  __syncthreads();

  if (t < 192){
    int q = t>>5, l = t&31;
    float v0 = (l      < NODES) ? S[q*56+l]    : -1e30f;
    float v1 = (l+32   < NODES) ? S[q*56+l+32] : -1e30f;
    float mx = fmaxf(v0, v1);
    #pragma unroll
    for (int o=16;o>0;o>>=1) mx = fmaxf(mx, __shfl_xor(mx, o, 32));
    float p0 = (l    < NODES) ? __expf(v0-mx) : 0.f;
    float p1 = (l+32 < NODES) ? __expf(v1-mx) : 0.f;
    float sm = p0 + p1;
    #pragma unroll
    for (int o=16;o>0;o>>=1) sm += __shfl_xor(sm, o, 32);
    float inv = 1.f/sm;
    if (l    < NODES) S[q*56+l]    = p0*inv;
    if (l+32 < NODES) S[q*56+l+32] = p1*inv;
  }
  __syncthreads();

  if (t < 192){
    int q = t>>5, oc = t&31;
    float a = 0.f;
    for (int k=0;k<NODES;k++) a = fmaf(S[q*56+k], V[k*33+oc], a);
    O[q*33+oc] = a;
  }
  __syncthreads();

  if (t < 192){
    int q = t>>5, oc = t&31;
    float a = bo[oc];
    #pragma unroll
    for (int c=0;c<HID;c++) a = fmaf(O[q*33+c], Wo[c*HID+oc], a);
    SO[t] = selu_f(a);
  }
  __syncthreads();

  if (t < 96){
    int j = t % 6, pp = t / 6;
    float a = 0.f;
    #pragma unroll
    for (int r=0;r<12;r++) a = fmaf(SO[pp*12+r], Wfc[(pp*12+r)*6+j], a);
    part[pp*6+j] = a;
  }
  __syncthreads();
  if (t < 6){
    float a = bfc[t];
    #pragma unroll
    for (int pp=0;pp<16;pp++) a += part[pp*6+t];
    out[g*6+t] = a;
  }
}

extern "C" void kernel_launch(void* const* d_in, const int* in_sizes, int n_in,
                              void* d_out, int out_size, void* d_ws, size_t ws_size,
                              hipStream_t stream)
{
  const float* x   = (const float*)d_in[0];
  const int*   eix = (const int*)d_in[1];
  const int*   shf = (const int*)d_in[2];
  const float* wl0 = (const float*)d_in[3];
  const float* bl0 = (const float*)d_in[4];
  const float* wr0 = (const float*)d_in[5];
  const float* wl  = (const float*)d_in[6];
  const float* bl  = (const float*)d_in[7];
  const float* wr  = (const float*)d_in[8];
  const float* wq  = (const float*)d_in[9];
  const float* bq  = (const float*)d_in[10];
  const float* wk  = (const float*)d_in[11];
  const float* bk  = (const float*)d_in[12];
  const float* wv  = (const float*)d_in[13];
  const float* bv  = (const float*)d_in[14];
  const float* wo  = (const float*)d_in[15];
  const float* bo  = (const float*)d_in[16];
  const float* wfc = (const float*)d_in[17];
  const float* bfc = (const float*)d_in[18];
  float* out = (float*)d_out;

  const int* esrc = eix;
  const int* edst = eix + ETOT;

  // workspace ~242.8 MB (< 252.3 MB known-available)
  char* p0 = (char*)d_ws;
  size_t used = 0;
  auto carve = [&](size_t bytes)->void*{
    void* r = (void*)(p0 + used);
    used += (bytes + 255) & ~(size_t)255;
    return r;
  };
  int*      off  = (int*)carve(sizeof(int)*(NTOT+1));     // CSR offsets (by dst)
  int*      offS = (int*)carve(sizeof(int)*(NTOT+1));     // CSC offsets (by src)
  uint32_t* mapS = (uint32_t*)carve(sizeof(uint32_t)*(size_t)ETOT);
  uint32_t* bm   = (uint32_t*)carve(sizeof(uint32_t)*NPART*BMW);
  f16*      EVa  = (f16*)carve((size_t)EVCAPE*HID*2);
  f16*      EVb  = (f16*)carve((size_t)EVCAPE*HID*2);
  f16*      h_a  = (f16*)carve(2*(size_t)NTOT*HID);
  f16*      h_b  = (f16*)carve(2*(size_t)NTOT*HID);
  f16*      jk16 = (f16*)carve(2*(size_t)NTOT*HID);
  f16*      EV16[2] = {EVa, EVb};
  float*    EV0[2]  = {(float*)EVa, (float*)EVb};   // layer0: 16 fp32 rows = 64B

  // build temps inside EV area (free until first layer0 scatter)
  int* sdeg = (int*)EVa;
  int* ddeg = sdeg + NTOT;
  int* pA   = ddeg + NTOT;

  hipMemsetAsync(sdeg, 0, sizeof(int)*2*NTOT, stream);
  hipMemsetAsync(bm, 0, sizeof(uint32_t)*NPART*BMW, stream);
  k_hist2<<<ETOT/256, 256, 0, stream>>>(esrc, edst, sdeg, ddeg);
  k_scan1<<<NCHUNK, 256, 0, stream>>>(sdeg, pA);
  k_scan2<<<1, 1024, 0, stream>>>(pA, NCHUNK);
  k_scan3<<<NCHUNK, 256, 0, stream>>>(sdeg, pA, offS);
  k_scan1<<<NCHUNK, 256, 0, stream>>>(ddeg, pA);
  k_scan2<<<1, 1024, 0, stream>>>(pA, NCHUNK);
  k_scan3<<<NCHUNK, 256, 0, stream>>>(ddeg, pA, off);
  hipMemcpyAsync(sdeg, offS, sizeof(int)*NTOT, hipMemcpyDeviceToDevice, stream);
  hipMemcpyAsync(ddeg, off,  sizeof(int)*NTOT, hipMemcpyDeviceToDevice, stream);
  k_fill2<<<ETOT/256, 256, 0, stream>>>(esrc, edst, sdeg, ddeg, mapS, bm);

  const int FATG = 4224;   // 3520 sc blocks + 704 red blocks (role = blockIdx%6)

  // layer 0: x -> h_a, jk  (pipelined sc0 || red0)
  for (int q=0; q<=NPART; q++){
    k_pipe0<<<FATG, 256, 0, stream>>>(x, h_a, jk16, off, offS, mapS, bm,
                                      EV0[q&1], EV0[(q+1)&1],
                                      wl0, bl0, wr0,
                                      (q<NPART)? q : -1, (q>0)? q-1 : -1);
  }
  // layers 1..4
  f16* hc = h_a; f16* hn = h_b;
  for (int l=0; l<4; l++){
    for (int q=0; q<=NPART; q++){
      k_pipe<<<FATG, 256, 0, stream>>>(hc, hn, jk16, off, offS, mapS, bm,
                                       EV16[q&1], EV16[(q+1)&1],
                                       wl + l*HID*HID, bl + l*HID, wr + l*HID*HID,
                                       (q<NPART)? q : -1, (q>0)? q-1 : -1);
    }
    f16* tmp = hc; hc = hn; hn = tmp;
  }
  k_attn<<<BGRAPH, 256, 0, stream>>>(jk16, x, shf,
                                     wq, bq, wk, bk, wv, bv, wo, bo, wfc, bfc, out);
}